// Round 13
// baseline (3026.953 us; speedup 1.0000x reference)
//
#include <hip/hip_runtime.h>
#include <hip/hip_cooperative_groups.h>

typedef __bf16 bf16;
typedef __bf16 bf16x8 __attribute__((ext_vector_type(8)));
typedef float f32x4 __attribute__((ext_vector_type(4)));
typedef unsigned short u16;
typedef unsigned int u32;
typedef unsigned long long u64;
typedef unsigned int u32x4 __attribute__((ext_vector_type(4)));

// Problem dims
#define TT 256
#define NTAGS 50

// Workspace layout (bytes) — r8/r10-proven offsets
#define OFF_WIH   0ull                        // bf16 [1024][1024]
#define OFF_WHH   2097152ull
#define OFF_WCH   4194304ull
#define OFF_WC2H  6291456ull
#define OFF_DW    8388608ull                  // bf16 [64][1024] (tags padded to 64)
#define OFF_XW    8519680ull                  // u64 [1024 rowtile][64 coltile][64 lane] packed acc-layout xw
#define OFF_HISTB 42074112ull                 // bf16 [256][64][1024] hy at step t (k_out input)
#define OFF_HB    75628544ull                 // bf16 [2][64][1024] h cross-block (slot0 = h0)
#define OFF_CB    75890688ull                 // bf16 [2][64][1024] c cross-block (slot0 = c0)
#define OFF_BAR   76152832ull                 // u32 [4][64][32]: 1 flag per 128B line
#define N_FLAG_WORDS (4 * 64 * 32)

// Agent-scope relaxed (L1/L2-bypassing, meet-at-L3) accessors — r5/r8-proven.
__device__ __forceinline__ u64 cohload(const u64* p) {
  return __hip_atomic_load(p, __ATOMIC_RELAXED, __HIP_MEMORY_SCOPE_AGENT);
}
__device__ __forceinline__ void cohstore(u64* p, u64 v) {
  __hip_atomic_store(p, v, __ATOMIC_RELAXED, __HIP_MEMORY_SCOPE_AGENT);
}
__device__ __forceinline__ u32x4 cohload_q4(const bf16* p) {
  union { u64 q[2]; u32x4 v; } u;
  const u64* q = (const u64*)p;
  u.q[0] = cohload(q);
  u.q[1] = cohload(q + 1);
  return u.v;
}
__device__ __forceinline__ float bf2f(u32 bits) {
  return __builtin_bit_cast(float, bits << 16);
}
// LDS write->read fence: TBAA can't see u16-store -> u64-load aliasing, so without
// this the compiler may omit the lgkmcnt wait (r12 bug: absmax 2.8e-2 stale tiles).
__device__ __forceinline__ void lds_fence() {
  asm volatile("s_waitcnt lgkmcnt(0)" ::: "memory");
  __builtin_amdgcn_sched_barrier(0);
}

// ---------------- prep: weights->bf16, h0/c0 slot0 init, barrier flags=0 ----------------
__global__ void k_prep(const float* __restrict__ wih, const float* __restrict__ whh,
                       const float* __restrict__ wch, const float* __restrict__ wc2h,
                       const float* __restrict__ dw, const float* __restrict__ h0,
                       const float* __restrict__ c0, char* __restrict__ ws) {
  const long N_W = 4194304, N_DW = 65536, N_S = 65536;
  const long TOT = N_W + N_DW + 2 * N_S + N_FLAG_WORDS;
  long stride = (long)gridDim.x * blockDim.x;
  for (long idx = (long)blockIdx.x * blockDim.x + threadIdx.x; idx < TOT; idx += stride) {
    if (idx < N_W) {
      long m = idx >> 20, e = idx & 1048575;
      const float* s = (m == 0) ? wih : (m == 1) ? whh : (m == 2) ? wch : wc2h;
      ((bf16*)(ws + OFF_WIH))[idx] = (bf16)s[e];
    } else if (idx < N_W + N_DW) {
      long j = idx - N_W; long r = j >> 10, e = j & 1023;
      ((bf16*)(ws + OFF_DW))[j] = (bf16)((r < NTAGS) ? dw[r * 1024 + e] : 0.f);
    } else if (idx < N_W + N_DW + N_S) {          // HB slot0 = h0
      long j = idx - N_W - N_DW;
      ((bf16*)(ws + OFF_HB))[j] = (bf16)h0[j];
    } else if (idx < N_W + N_DW + 2 * N_S) {      // CB slot0 = c0
      long j = idx - N_W - N_DW - N_S;
      ((bf16*)(ws + OFF_CB))[j] = (bf16)c0[j];
    } else {                                      // flags = 0 (replay safety)
      long j = idx - N_W - N_DW - 2 * N_S;
      ((u32*)(ws + OFF_BAR))[j] = 0u;
    }
  }
}

// ---------------- XW = emb[X] @ Wih^T + b_ih + b_hh, stored PACKED in acc layout ----------------
// xwA[rowtile(1024)][coltile(64)][lane(64)] : u64 = 4 bf16 (acc regs r=0..3), bias fused.
__global__ __launch_bounds__(256, 1) void k_xw(const int* __restrict__ X,
                                               const float* __restrict__ emb,
                                               const float* __restrict__ b_ih,
                                               const float* __restrict__ b_hh,
                                               char* __restrict__ ws) {
  const bf16* wih = (const bf16*)(ws + OFF_WIH);
  u64* xwA = (u64*)(ws + OFF_XW);
  int l = threadIdx.x & 63, wv = threadIdx.x >> 6;
  int i0 = blockIdx.x * 64 + wv * 16;
  const float* ap = emb + (long)X[i0 + (l & 15)] * 1024 + ((l >> 4) * 8);

  bf16x8 a_reg[32];
#pragma unroll
  for (int k = 0; k < 32; ++k) {
    f32x4 f0 = *(const f32x4*)(ap + k * 32);
    f32x4 f1 = *(const f32x4*)(ap + k * 32 + 4);
    bf16x8 a;
#pragma unroll
    for (int q = 0; q < 4; ++q) { a[q] = (bf16)f0[q]; a[4 + q] = (bf16)f1[q]; }
    a_reg[k] = a;
  }

  f32x4 zero = {0.f, 0.f, 0.f, 0.f};
  long rowtile = (long)blockIdx.x * 4 + wv;
  for (int ct = 0; ct < 16; ++ct) {
    int h0 = ct * 64;
    const bf16* bp = wih + (long)(h0 + (l & 15)) * 1024 + ((l >> 4) * 8);
    f32x4 acc[4] = {zero, zero, zero, zero};
#pragma unroll
    for (int k = 0; k < 32; ++k)
#pragma unroll
      for (int j = 0; j < 4; ++j) {
        bf16x8 b = *(const bf16x8*)(bp + j * 16 * 1024 + k * 32);
        acc[j] = __builtin_amdgcn_mfma_f32_16x16x32_bf16(a_reg[k], b, acc[j], 0, 0, 0);
      }
#pragma unroll
    for (int j = 0; j < 4; ++j) {
      int col = h0 + j * 16 + (l & 15);
      float bias = b_ih[col] + b_hh[col];
      u64 pk = 0;
#pragma unroll
      for (int r = 0; r < 4; ++r)
        pk |= (u64)__builtin_bit_cast(u16, (bf16)(acc[j][r] + bias)) << (16 * r);
      xwA[(rowtile * 64 + (ct * 4 + j)) * 64 + l] = pk;
    }
  }
}

// ---------------- recurrence: 4 groups x 64 SINGLE-WAVE blocks ----------------
// r12 structure + the LDS write->read fences (TBAA fix). One wave per block:
//  - no __syncthreads; elementwise directly on MFMA acc registers
//  - publish via in-wave LDS transpose (explicitly lgkmcnt-fenced)
//  - all 64 lanes poll all 64 flags in one parallel shot
//  - weights stream from L2; cy frags (128 VGPR) carried B->A
//  - c-MFMA stream runs BEFORE the h-poll to fill the wait
// Exchange protocol (publish -> vmcnt(0) -> flag -> poll) byte-identical to r10.
__global__ __launch_bounds__(64, 1) void k_rnn(const float* __restrict__ b_ch,
                                               const float* __restrict__ b_c2h,
                                               const float* __restrict__ c0,
                                               char* __restrict__ ws) {
  const u64* xwA = (const u64*)(ws + OFF_XW);
  bf16* histb = (bf16*)(ws + OFF_HISTB);
  bf16* HB = (bf16*)(ws + OFF_HB);
  bf16* CB = (bf16*)(ws + OFF_CB);
  int g = blockIdx.x & 3, j = blockIdx.x >> 2;
  u32* flags = (u32*)(ws + OFF_BAR) + g * 64 * 32;

  int l = threadIdx.x;
  int b0 = g * 16, n0 = j * 16;
  int lane_r = l & 15, k8 = (l >> 4) * 8;
  long arow = (long)(b0 + lane_r) * 1024 + k8;    // A-frag base (h/c rows = batch)
  long wrow = (long)(n0 + lane_r) * 1024 + k8;    // B-frag base (weight rows = cols)
  const bf16* whh  = (const bf16*)(ws + OFF_WHH)  + wrow;
  const bf16* wch  = (const bf16*)(ws + OFF_WCH)  + wrow;
  const bf16* wc2h = (const bf16*)(ws + OFF_WC2H) + wrow;

  __shared__ u16 xfs[256];   // 16x16 tile, in-wave transpose staging

  int er = l >> 4, ec = l & 15;   // acc element: rows er*4+r, col ec
  float c_reg[4];
#pragma unroll
  for (int r = 0; r < 4; ++r)
    c_reg[r] = c0[(b0 + er * 4 + r) * 1024 + n0 + ec];
  float bch_v = b_ch[n0 + ec], bc2h_v = b_c2h[n0 + ec];
  f32x4 zero = {0.f, 0.f, 0.f, 0.f};

  // initial c(0) fragments (K=1024 -> 32 q4 = 128 VGPR, carried across phases)
  u32x4 cfr[32];
#pragma unroll
  for (int kk = 0; kk < 32; ++kk)
    cfr[kk] = cohload_q4(CB + arow + kk * 32);

  int srow = l >> 2, scol = (l & 3) * 4;   // u64 publish mapping

  for (int t = 0; t < TT; ++t) {
    u32 tkH = 2u * t, tkA = 2u * t + 1u, tkB = 2u * t + 2u;
    long slot1 = (long)((t + 1) & 1) * 65536;
    u64 xwp = xwA[((long)(t * 4 + g) * 64 + j) * 64 + l];   // issued early

    // ---- phase A part 1 (pre-poll): accC = c(t) @ Wch from registers + L2 weights
    f32x4 c0a = zero, c1a = zero;
#pragma unroll
    for (int kk = 0; kk < 32; ++kk) {
      u32x4 w = *(const u32x4*)(wch + kk * 32);
      if (kk & 1)
        c1a = __builtin_amdgcn_mfma_f32_16x16x32_bf16(
            __builtin_bit_cast(bf16x8, cfr[kk]), __builtin_bit_cast(bf16x8, w), c1a, 0, 0, 0);
      else
        c0a = __builtin_amdgcn_mfma_f32_16x16x32_bf16(
            __builtin_bit_cast(bf16x8, cfr[kk]), __builtin_bit_cast(bf16x8, w), c0a, 0, 0, 0);
    }

    // ---- poll h(t): 64 lanes x 64 flags, one parallel shot
    {
      const u32* my = &flags[l * 32];
      while (!__all(__hip_atomic_load(my, __ATOMIC_RELAXED, __HIP_MEMORY_SCOPE_AGENT) >= tkH))
        __builtin_amdgcn_s_sleep(1);
    }
    asm volatile("" ::: "memory");

    // ---- phase A part 2: accH = h(t) @ Whh (streamed)
    const bf16* hx = HB + (long)(t & 1) * 65536 + arow;
    f32x4 h0a = zero, h1a = zero;
#pragma unroll
    for (int kk = 0; kk < 32; ++kk) {
      u32x4 hf = cohload_q4(hx + kk * 32);
      u32x4 w = *(const u32x4*)(whh + kk * 32);
      if (kk & 1)
        h1a = __builtin_amdgcn_mfma_f32_16x16x32_bf16(
            __builtin_bit_cast(bf16x8, hf), __builtin_bit_cast(bf16x8, w), h1a, 0, 0, 0);
      else
        h0a = __builtin_amdgcn_mfma_f32_16x16x32_bf16(
            __builtin_bit_cast(bf16x8, hf), __builtin_bit_cast(bf16x8, w), h0a, 0, 0, 0);
    }

    // ---- elementwise on acc registers; pack cy via in-wave LDS transpose
    float pre_s[4], cy_s[4];
#pragma unroll
    for (int r = 0; r < 4; ++r) {
      float pre = h0a[r] + h1a[r] + bf2f((u32)(xwp >> (16 * r)) & 0xFFFFu);
      float cgm = c0a[r] + c1a[r] + bch_v;
      float gif = 1.f / (1.f + expf(-(pre + cgm)));
      float cy = gif * (c_reg[r] + tanhf(pre));
      c_reg[r] = cy;
      pre_s[r] = pre;
      cy_s[r] = cy;
      xfs[(er * 4 + r) * 16 + ec] = __builtin_bit_cast(u16, (bf16)cy);
    }
    lds_fence();                                    // TBAA fix: order writes before read
    u64 pkc = ((const u64*)xfs)[l];                 // rows l>>2, cols (l&3)*4..+3
    cohstore((u64*)(CB + slot1 + (long)(b0 + srow) * 1024 + n0 + scol), pkc);
    asm volatile("s_waitcnt vmcnt(0)" ::: "memory");
    if (l == 0)
      __hip_atomic_store(&flags[j * 32], tkA, __ATOMIC_RELAXED, __HIP_MEMORY_SCOPE_AGENT);
    {
      const u32* my = &flags[l * 32];
      while (!__all(__hip_atomic_load(my, __ATOMIC_RELAXED, __HIP_MEMORY_SCOPE_AGENT) >= tkA))
        __builtin_amdgcn_s_sleep(1);
    }
    asm volatile("" ::: "memory");

    // ---- phase B: o = cy(t+1) @ Wc2h; cfr refilled (becomes next step's c operand)
    const bf16* cyp = CB + slot1 + arow;
    f32x4 o0a = zero, o1a = zero;
#pragma unroll
    for (int kk = 0; kk < 32; ++kk) {
      cfr[kk] = cohload_q4(cyp + kk * 32);
      u32x4 w = *(const u32x4*)(wc2h + kk * 32);
      if (kk & 1)
        o1a = __builtin_amdgcn_mfma_f32_16x16x32_bf16(
            __builtin_bit_cast(bf16x8, cfr[kk]), __builtin_bit_cast(bf16x8, w), o1a, 0, 0, 0);
      else
        o0a = __builtin_amdgcn_mfma_f32_16x16x32_bf16(
            __builtin_bit_cast(bf16x8, cfr[kk]), __builtin_bit_cast(bf16x8, w), o0a, 0, 0, 0);
    }
#pragma unroll
    for (int r = 0; r < 4; ++r) {
      float o = o0a[r] + o1a[r] + bc2h_v;
      float og = 1.f / (1.f + expf(-(pre_s[r] + o)));
      float hy = og * tanhf(cy_s[r]);
      xfs[(er * 4 + r) * 16 + ec] = __builtin_bit_cast(u16, (bf16)hy);
    }
    lds_fence();                                    // TBAA fix: order writes before read
    u64 pkh = ((const u64*)xfs)[l];
    *(u64*)(histb + (long)t * 65536 + (long)(b0 + srow) * 1024 + n0 + scol) = pkh;
    if (t < TT - 1) {
      cohstore((u64*)(HB + slot1 + (long)(b0 + srow) * 1024 + n0 + scol), pkh);
      asm volatile("s_waitcnt vmcnt(0)" ::: "memory");
      if (l == 0)
        __hip_atomic_store(&flags[j * 32], tkB, __ATOMIC_RELAXED, __HIP_MEMORY_SCOPE_AGENT);
      // poll for tkB happens at next iteration's tkH (== tkB)
    }
  }
}

// ---------------- dense + softmax ----------------
__global__ __launch_bounds__(256) void k_out(const float* __restrict__ dense_b,
                                             const char* __restrict__ ws,
                                             float* __restrict__ out) {
  const bf16* h  = (const bf16*)(ws + OFF_HISTB);  // slot t = hy at step t
  const bf16* dw = (const bf16*)(ws + OFF_DW);
  int l = threadIdx.x & 63, wv = threadIdx.x >> 6;
  int i0 = blockIdx.x * 64 + wv * 16;
  const bf16* ap = h  + (long)(i0 + (l & 15)) * 1024 + ((l >> 4) * 8);
  const bf16* bp = dw + (long)(l & 15) * 1024 + ((l >> 4) * 8);
  f32x4 zero = {0.f, 0.f, 0.f, 0.f};
  f32x4 acc[4] = {zero, zero, zero, zero};
  for (int k = 0; k < 1024; k += 32) {
    bf16x8 a = *(const bf16x8*)(ap + k);
#pragma unroll
    for (int j = 0; j < 4; ++j) {
      bf16x8 b = *(const bf16x8*)(bp + j * 16 * 1024 + k);
      acc[j] = __builtin_amdgcn_mfma_f32_16x16x32_bf16(a, b, acc[j], 0, 0, 0);
    }
  }
  int tag0 = l & 15;
#pragma unroll
  for (int r = 0; r < 4; ++r) {
    int row = i0 + (l >> 4) * 4 + r;
    float lg[4], ex[4];
    float mx = -1e30f;
#pragma unroll
    for (int j = 0; j < 4; ++j) {
      int tag = j * 16 + tag0;
      lg[j] = (tag < NTAGS) ? (acc[j][r] + dense_b[tag]) : -1e30f;
      mx = fmaxf(mx, lg[j]);
    }
    for (int m = 1; m < 16; m <<= 1) mx = fmaxf(mx, __shfl_xor(mx, m, 64));
    float s = 0.f;
#pragma unroll
    for (int j = 0; j < 4; ++j) {
      int tag = j * 16 + tag0;
      ex[j] = (tag < NTAGS) ? expf(lg[j] - mx) : 0.f;
      s += ex[j];
    }
    for (int m = 1; m < 16; m <<= 1) s += __shfl_xor(s, m, 64);
    float inv = 1.f / s;
#pragma unroll
    for (int j = 0; j < 4; ++j) {
      int tag = j * 16 + tag0;
      if (tag < NTAGS) out[(long)row * 50 + tag] = ex[j] * inv;
    }
  }
}

extern "C" void kernel_launch(void* const* d_in, const int* in_sizes, int n_in,
                              void* d_out, int out_size, void* d_ws, size_t ws_size,
                              hipStream_t stream) {
  const int*   X        = (const int*)d_in[0];
  // d_in[1] = lengths (unused; all == T)
  const float* embedding = (const float*)d_in[2];
  const float* w_ih  = (const float*)d_in[3];
  const float* w_hh  = (const float*)d_in[4];
  const float* w_ch  = (const float*)d_in[5];
  const float* w_c2h = (const float*)d_in[6];
  const float* b_ih  = (const float*)d_in[7];
  const float* b_hh  = (const float*)d_in[8];
  const float* b_ch  = (const float*)d_in[9];
  const float* b_c2h = (const float*)d_in[10];
  const float* dense_w = (const float*)d_in[11];
  const float* dense_b = (const float*)d_in[12];
  const float* h0 = (const float*)d_in[13];
  const float* c0 = (const float*)d_in[14];
  char* ws = (char*)d_ws;
  float* out = (float*)d_out;

  k_prep<<<2048, 256, 0, stream>>>(w_ih, w_hh, w_ch, w_c2h, dense_w, h0, c0, ws);
  k_xw<<<256, 256, 0, stream>>>(X, embedding, b_ih, b_hh, ws);

  void* args[] = {(void*)&b_ch, (void*)&b_c2h, (void*)&c0, (void*)&ws};
  hipLaunchCooperativeKernel((const void*)k_rnn, dim3(256), dim3(64), args, 0, stream);

  k_out<<<256, 256, 0, stream>>>(dense_b, ws, out);
}

// Round 15
// 2287.477 us; speedup vs baseline: 1.3233x; 1.3233x over previous
//
#include <hip/hip_runtime.h>
#include <hip/hip_cooperative_groups.h>

typedef __bf16 bf16;
typedef __bf16 bf16x8 __attribute__((ext_vector_type(8)));
typedef float f32x4 __attribute__((ext_vector_type(4)));
typedef unsigned int u32;
typedef unsigned long long u64;
typedef unsigned int u32x4 __attribute__((ext_vector_type(4)));

// Problem dims
#define TT 256
#define NTAGS 50

// Workspace layout (bytes) — r8-proven
#define OFF_WIH   0ull                        // bf16 [1024][1024]
#define OFF_WHH   2097152ull
#define OFF_WCH   4194304ull
#define OFF_WC2H  6291456ull
#define OFF_DW    8388608ull                  // bf16 [64][1024] (tags padded to 64)
#define OFF_XW    8519680ull                  // bf16 [16384][1024]
#define OFF_HISTB 42074112ull                 // bf16 [256][64][1024] hy at step t (k_out input)
#define OFF_HB    75628544ull                 // bf16 [2][64][1024] h cross-block (slot0 = h0)
#define OFF_CB    75890688ull                 // bf16 [2][64][1024] c cross-block (slot0 = c0)
#define OFF_BAR   76152832ull                 // u32 [4][64][32]: 1 flag per 128B line
#define N_FLAG_WORDS (4 * 64 * 32)

// Agent-scope relaxed (L1/L2-bypassing, meet-at-L3) accessors — r5/r8-proven.
__device__ __forceinline__ u64 cohload(const u64* p) {
  return __hip_atomic_load(p, __ATOMIC_RELAXED, __HIP_MEMORY_SCOPE_AGENT);
}
__device__ __forceinline__ void cohstore(u64* p, u64 v) {
  __hip_atomic_store(p, v, __ATOMIC_RELAXED, __HIP_MEMORY_SCOPE_AGENT);
}
__device__ __forceinline__ bf16x8 cohload_v8(const bf16* p) {
  union { u64 q[2]; bf16x8 v; } u;
  const u64* q = (const u64*)p;
  u.q[0] = cohload(q);
  u.q[1] = cohload(q + 1);
  return u.v;
}
__device__ __forceinline__ u32x4 cohload_q4(const bf16* p) {
  union { u64 q[2]; u32x4 v; } u;
  const u64* q = (const u64*)p;
  u.q[0] = cohload(q);
  u.q[1] = cohload(q + 1);
  return u.v;
}

// ---------------- prep: weights->bf16, h0/c0 slot0 init, barrier flags=0 ----------------
__global__ void k_prep(const float* __restrict__ wih, const float* __restrict__ whh,
                       const float* __restrict__ wch, const float* __restrict__ wc2h,
                       const float* __restrict__ dw, const float* __restrict__ h0,
                       const float* __restrict__ c0, char* __restrict__ ws) {
  const long N_W = 4194304, N_DW = 65536, N_S = 65536;
  const long TOT = N_W + N_DW + 2 * N_S + N_FLAG_WORDS;
  long stride = (long)gridDim.x * blockDim.x;
  for (long idx = (long)blockIdx.x * blockDim.x + threadIdx.x; idx < TOT; idx += stride) {
    if (idx < N_W) {
      long m = idx >> 20, e = idx & 1048575;
      const float* s = (m == 0) ? wih : (m == 1) ? whh : (m == 2) ? wch : wc2h;
      ((bf16*)(ws + OFF_WIH))[idx] = (bf16)s[e];
    } else if (idx < N_W + N_DW) {
      long j = idx - N_W; long r = j >> 10, e = j & 1023;
      ((bf16*)(ws + OFF_DW))[j] = (bf16)((r < NTAGS) ? dw[r * 1024 + e] : 0.f);
    } else if (idx < N_W + N_DW + N_S) {          // HB slot0 = h0
      long j = idx - N_W - N_DW;
      ((bf16*)(ws + OFF_HB))[j] = (bf16)h0[j];
    } else if (idx < N_W + N_DW + 2 * N_S) {      // CB slot0 = c0
      long j = idx - N_W - N_DW - N_S;
      ((bf16*)(ws + OFF_CB))[j] = (bf16)c0[j];
    } else {                                      // flags = 0 (replay safety)
      long j = idx - N_W - N_DW - 2 * N_S;
      ((u32*)(ws + OFF_BAR))[j] = 0u;
    }
  }
}

// ---------------- XW = emb[X] @ Wih^T + b_ih + b_hh ----------------
// 256 blocks; block = 64 rows. A gathered ONCE into 128 VGPRs of bf16 frags;
// inner loop streams B over 16 column tiles from L2.
__global__ __launch_bounds__(256, 1) void k_xw(const int* __restrict__ X,
                                               const float* __restrict__ emb,
                                               const float* __restrict__ b_ih,
                                               const float* __restrict__ b_hh,
                                               char* __restrict__ ws) {
  const bf16* wih = (const bf16*)(ws + OFF_WIH);
  bf16* xw = (bf16*)(ws + OFF_XW);
  int l = threadIdx.x & 63, wv = threadIdx.x >> 6;
  int i0 = blockIdx.x * 64 + wv * 16;
  const float* ap = emb + (long)X[i0 + (l & 15)] * 1024 + ((l >> 4) * 8);

  // A tile (16 rows x K=1024) -> bf16 fragments in registers (32 x bf16x8)
  bf16x8 a_reg[32];
#pragma unroll
  for (int k = 0; k < 32; ++k) {
    f32x4 f0 = *(const f32x4*)(ap + k * 32);
    f32x4 f1 = *(const f32x4*)(ap + k * 32 + 4);
    bf16x8 a;
#pragma unroll
    for (int q = 0; q < 4; ++q) { a[q] = (bf16)f0[q]; a[4 + q] = (bf16)f1[q]; }
    a_reg[k] = a;
  }

  f32x4 zero = {0.f, 0.f, 0.f, 0.f};
  for (int ct = 0; ct < 16; ++ct) {
    int h0 = ct * 64;
    const bf16* bp = wih + (long)(h0 + (l & 15)) * 1024 + ((l >> 4) * 8);
    f32x4 acc[4] = {zero, zero, zero, zero};
#pragma unroll
    for (int k = 0; k < 32; ++k)
#pragma unroll
      for (int j = 0; j < 4; ++j) {
        bf16x8 b = *(const bf16x8*)(bp + j * 16 * 1024 + k * 32);
        acc[j] = __builtin_amdgcn_mfma_f32_16x16x32_bf16(a_reg[k], b, acc[j], 0, 0, 0);
      }
#pragma unroll
    for (int j = 0; j < 4; ++j)
#pragma unroll
      for (int r = 0; r < 4; ++r) {
        int row = i0 + (l >> 4) * 4 + r;
        int col = h0 + j * 16 + (l & 15);
        xw[(long)row * 1024 + col] = (bf16)(acc[j][r] + b_ih[col] + b_hh[col]);
      }
  }
}

// ---------------- recurrence: 4 indep batch-groups x 64 blocks (r10-proven) ----------------
// group g = blockIdx&3 owns batch rows [16g,16g+16); block j = blockIdx>>2 owns h-slice
// [16j,16j+16). 4 waves K-split (256 each).
//  (1) weights pinned in VGPRs with IN-LOOP asm (defeats rematerialization),
//  (2) phase-B c fragments carried in registers into next phase A,
//  (3) histb store tucked between flag-store and poll (hides under the wait).
__global__ __launch_bounds__(256, 1) void k_rnn(const float* __restrict__ b_ch,
                                                const float* __restrict__ b_c2h,
                                                const float* __restrict__ c0,
                                                char* __restrict__ ws) {
  const bf16* xw = (const bf16*)(ws + OFF_XW);
  bf16* histb = (bf16*)(ws + OFF_HISTB);
  bf16* HB = (bf16*)(ws + OFF_HB);
  bf16* CB = (bf16*)(ws + OFF_CB);
  int g = blockIdx.x & 3, j = blockIdx.x >> 2;
  u32* flags = (u32*)(ws + OFF_BAR) + g * 64 * 32;

  int l = threadIdx.x & 63, wv = threadIdx.x >> 6;
  int b0 = g * 16, h0b = j * 16;
  int e = threadIdx.x;
  int eoff = (b0 + (e >> 4)) * 1024 + h0b + (e & 15);
  int gh = h0b + (e & 15);

  __shared__ float red[4][2][256];
  __shared__ bf16 xfer[256];   // 16x16 outgoing tile staging

  int lane_r = l & 15;
  int koff = wv * 256 + ((l >> 4) * 8);
  long arow = (long)(b0 + lane_r) * 1024 + koff;

  // weight fragments -> registers (96 VGPRs of bf16), plus rolling c fragments.
  u32x4 whh_r[8], wch_r[8], wc2h_r[8], cfr[8];
  {
    const bf16* p1 = (const bf16*)(ws + OFF_WHH)  + (long)(h0b + lane_r) * 1024 + koff;
    const bf16* p2 = (const bf16*)(ws + OFF_WCH)  + (long)(h0b + lane_r) * 1024 + koff;
    const bf16* p3 = (const bf16*)(ws + OFF_WC2H) + (long)(h0b + lane_r) * 1024 + koff;
#pragma unroll
    for (int kk = 0; kk < 8; ++kk) {
      whh_r[kk]  = *(const u32x4*)(p1 + kk * 32);
      wch_r[kk]  = *(const u32x4*)(p2 + kk * 32);
      wc2h_r[kk] = *(const u32x4*)(p3 + kk * 32);
      cfr[kk] = cohload_q4(CB + arow + kk * 32);   // c(0) from slot0
    }
  }

  float bch_v = b_ch[gh], bc2h_v = b_c2h[gh];
  float c_reg = c0[eoff];
  f32x4 zero = {0.f, 0.f, 0.f, 0.f};

  for (int t = 0; t < TT; ++t) {
    // In-loop pins: the empty asm "modifies" the frags every iteration, so the
    // compiler must keep them resident (cannot re-load from memory).
    asm volatile("" : "+v"(whh_r[0]), "+v"(whh_r[1]), "+v"(whh_r[2]), "+v"(whh_r[3]),
                      "+v"(whh_r[4]), "+v"(whh_r[5]), "+v"(whh_r[6]), "+v"(whh_r[7]),
                      "+v"(wch_r[0]), "+v"(wch_r[1]), "+v"(wch_r[2]), "+v"(wch_r[3]),
                      "+v"(wch_r[4]), "+v"(wch_r[5]), "+v"(wch_r[6]), "+v"(wch_r[7]));
    asm volatile("" : "+v"(wc2h_r[0]), "+v"(wc2h_r[1]), "+v"(wc2h_r[2]), "+v"(wc2h_r[3]),
                      "+v"(wc2h_r[4]), "+v"(wc2h_r[5]), "+v"(wc2h_r[6]), "+v"(wc2h_r[7]));
    asm volatile("" : "+v"(cfr[0]), "+v"(cfr[1]), "+v"(cfr[2]), "+v"(cfr[3]),
                      "+v"(cfr[4]), "+v"(cfr[5]), "+v"(cfr[6]), "+v"(cfr[7]));

    long slot1 = (long)((t + 1) & 1) * 65536;
    float xwv = (float)xw[(long)t * 65536 + eoff];
    u32 tkA = 2u * t + 1u, tkB = 2u * t + 2u;
    const bf16* hx = HB + (long)(t & 1) * 65536;

    // ---- phase A: pre = h(t)@Whh (+xw), cg = c(t)@Wch (c frags already in regs)
    f32x4 ap_ = zero, ac_ = zero;
#pragma unroll
    for (int kk = 0; kk < 8; ++kk) {
      bf16x8 a1 = cohload_v8(hx + arow + kk * 32);
      ap_ = __builtin_amdgcn_mfma_f32_16x16x32_bf16(
          a1, __builtin_bit_cast(bf16x8, whh_r[kk]), ap_, 0, 0, 0);
      ac_ = __builtin_amdgcn_mfma_f32_16x16x32_bf16(
          __builtin_bit_cast(bf16x8, cfr[kk]), __builtin_bit_cast(bf16x8, wch_r[kk]), ac_, 0, 0, 0);
    }
#pragma unroll
    for (int r = 0; r < 4; ++r) {
      int ei = ((l >> 4) * 4 + r) * 16 + (l & 15);
      red[wv][0][ei] = ap_[r];
      red[wv][1][ei] = ac_[r];
    }
    __syncthreads();
    float pre = red[0][0][e] + red[1][0][e] + red[2][0][e] + red[3][0][e] + xwv;
    float cgm = red[0][1][e] + red[1][1][e] + red[2][1][e] + red[3][1][e] + bch_v;
    float gif = 1.f / (1.f + expf(-(pre + cgm)));
    float cy = gif * (c_reg + tanhf(pre));
    c_reg = cy;
    xfer[e] = (bf16)cy;
    __syncthreads();                    // xfer ready; red reads done
    if (e < 64)
      cohstore((u64*)(CB + slot1 + (long)(b0 + (e >> 2)) * 1024 + h0b) + (e & 3),
               ((u64*)xfer)[e]);
    asm volatile("s_waitcnt vmcnt(0)" ::: "memory");   // tile stores ack'd @L3
    if (e == 0)
      __hip_atomic_store(&flags[j * 32], tkA, __ATOMIC_RELAXED, __HIP_MEMORY_SCOPE_AGENT);
    if (e < 64) {
      const u32* my = &flags[e * 32];
      while (!__all(__hip_atomic_load(my, __ATOMIC_RELAXED, __HIP_MEMORY_SCOPE_AGENT) >= tkA))
        __builtin_amdgcn_s_sleep(1);
    }
    asm volatile("" ::: "memory");
    __syncthreads();

    // ---- phase B: o = cy(t+1)@Wc2h; keep cy frags for next step's phase A
    f32x4 ao = zero;
#pragma unroll
    for (int kk = 0; kk < 8; ++kk) {
      cfr[kk] = cohload_q4(CB + slot1 + arow + kk * 32);
      ao = __builtin_amdgcn_mfma_f32_16x16x32_bf16(
          __builtin_bit_cast(bf16x8, cfr[kk]), __builtin_bit_cast(bf16x8, wc2h_r[kk]), ao, 0, 0, 0);
    }
#pragma unroll
    for (int r = 0; r < 4; ++r)
      red[wv][0][((l >> 4) * 4 + r) * 16 + (l & 15)] = ao[r];
    __syncthreads();
    float o = red[0][0][e] + red[1][0][e] + red[2][0][e] + red[3][0][e] + bc2h_v;
    float og = 1.f / (1.f + expf(-(pre + o)));
    bf16 hb = (bf16)(og * tanhf(cy));
    xfer[e] = hb;
    __syncthreads();
    if (t < TT - 1) {
      if (e < 64)
        cohstore((u64*)(HB + slot1 + (long)(b0 + (e >> 2)) * 1024 + h0b) + (e & 3),
                 ((u64*)xfer)[e]);
      asm volatile("s_waitcnt vmcnt(0)" ::: "memory");
      if (e == 0)
        __hip_atomic_store(&flags[j * 32], tkB, __ATOMIC_RELAXED, __HIP_MEMORY_SCOPE_AGENT);
      histb[(long)t * 65536 + eoff] = hb;   // fire-and-forget; hides under the poll
      if (e < 64) {
        const u32* my = &flags[e * 32];
        while (!__all(__hip_atomic_load(my, __ATOMIC_RELAXED, __HIP_MEMORY_SCOPE_AGENT) >= tkB))
          __builtin_amdgcn_s_sleep(1);
      }
      asm volatile("" ::: "memory");
      __syncthreads();
    } else {
      histb[(long)t * 65536 + eoff] = hb;
    }
  }
}

// ---------------- dense + softmax ----------------
__global__ __launch_bounds__(256) void k_out(const float* __restrict__ dense_b,
                                             const char* __restrict__ ws,
                                             float* __restrict__ out) {
  const bf16* h  = (const bf16*)(ws + OFF_HISTB);  // slot t = hy at step t
  const bf16* dw = (const bf16*)(ws + OFF_DW);
  int l = threadIdx.x & 63, wv = threadIdx.x >> 6;
  int i0 = blockIdx.x * 64 + wv * 16;
  const bf16* ap = h  + (long)(i0 + (l & 15)) * 1024 + ((l >> 4) * 8);
  const bf16* bp = dw + (long)(l & 15) * 1024 + ((l >> 4) * 8);
  f32x4 zero = {0.f, 0.f, 0.f, 0.f};
  f32x4 acc[4] = {zero, zero, zero, zero};
  for (int k = 0; k < 1024; k += 32) {
    bf16x8 a = *(const bf16x8*)(ap + k);
#pragma unroll
    for (int j = 0; j < 4; ++j) {
      bf16x8 b = *(const bf16x8*)(bp + j * 16 * 1024 + k);
      acc[j] = __builtin_amdgcn_mfma_f32_16x16x32_bf16(a, b, acc[j], 0, 0, 0);
    }
  }
  int tag0 = l & 15;
#pragma unroll
  for (int r = 0; r < 4; ++r) {
    int row = i0 + (l >> 4) * 4 + r;
    float lg[4], ex[4];
    float mx = -1e30f;
#pragma unroll
    for (int j = 0; j < 4; ++j) {
      int tag = j * 16 + tag0;
      lg[j] = (tag < NTAGS) ? (acc[j][r] + dense_b[tag]) : -1e30f;
      mx = fmaxf(mx, lg[j]);
    }
    for (int m = 1; m < 16; m <<= 1) mx = fmaxf(mx, __shfl_xor(mx, m, 64));
    float s = 0.f;
#pragma unroll
    for (int j = 0; j < 4; ++j) {
      int tag = j * 16 + tag0;
      ex[j] = (tag < NTAGS) ? expf(lg[j] - mx) : 0.f;
      s += ex[j];
    }
    for (int m = 1; m < 16; m <<= 1) s += __shfl_xor(s, m, 64);
    float inv = 1.f / s;
#pragma unroll
    for (int j = 0; j < 4; ++j) {
      int tag = j * 16 + tag0;
      if (tag < NTAGS) out[(long)row * 50 + tag] = ex[j] * inv;
    }
  }
}

extern "C" void kernel_launch(void* const* d_in, const int* in_sizes, int n_in,
                              void* d_out, int out_size, void* d_ws, size_t ws_size,
                              hipStream_t stream) {
  const int*   X        = (const int*)d_in[0];
  // d_in[1] = lengths (unused; all == T)
  const float* embedding = (const float*)d_in[2];
  const float* w_ih  = (const float*)d_in[3];
  const float* w_hh  = (const float*)d_in[4];
  const float* w_ch  = (const float*)d_in[5];
  const float* w_c2h = (const float*)d_in[6];
  const float* b_ih  = (const float*)d_in[7];
  const float* b_hh  = (const float*)d_in[8];
  const float* b_ch  = (const float*)d_in[9];
  const float* b_c2h = (const float*)d_in[10];
  const float* dense_w = (const float*)d_in[11];
  const float* dense_b = (const float*)d_in[12];
  const float* h0 = (const float*)d_in[13];
  const float* c0 = (const float*)d_in[14];
  char* ws = (char*)d_ws;
  float* out = (float*)d_out;

  k_prep<<<2048, 256, 0, stream>>>(w_ih, w_hh, w_ch, w_c2h, dense_w, h0, c0, ws);
  k_xw<<<256, 256, 0, stream>>>(X, embedding, b_ih, b_hh, ws);

  void* args[] = {(void*)&b_ch, (void*)&b_c2h, (void*)&c0, (void*)&ws};
  hipLaunchCooperativeKernel((const void*)k_rnn, dim3(256), dim3(256), args, 0, stream);

  k_out<<<256, 256, 0, stream>>>(dense_b, ws, out);
}

// Round 16
// 2268.558 us; speedup vs baseline: 1.3343x; 1.0083x over previous
//
#include <hip/hip_runtime.h>
#include <hip/hip_cooperative_groups.h>

typedef __bf16 bf16;
typedef __bf16 bf16x8 __attribute__((ext_vector_type(8)));
typedef float f32x4 __attribute__((ext_vector_type(4)));
typedef unsigned int u32;
typedef unsigned long long u64;
typedef unsigned int u32x4 __attribute__((ext_vector_type(4)));

// Problem dims
#define TT 256
#define NTAGS 50

// Workspace layout (bytes) — r8/r10-proven offsets
#define OFF_WIH   0ull                        // bf16 [1024][1024]
#define OFF_WHH   2097152ull
#define OFF_WCH   4194304ull
#define OFF_WC2H  6291456ull
#define OFF_DW    8388608ull                  // bf16 [64][1024] (tags padded to 64)
#define OFF_XW    8519680ull                  // bf16 [16384][1024]
#define OFF_HISTB 42074112ull                 // bf16 [256][64][1024]; ALSO reused as the
                                              // EMB staging buffer (k_prep writes gathered
                                              // bf16 emb here; k_xw consumes it; k_rnn then
                                              // overwrites with hy history for k_out)
#define OFF_HB    75628544ull                 // bf16 [2][64][1024] h cross-block (slot0 = h0)
#define OFF_CB    75890688ull                 // bf16 [2][64][1024] c cross-block (slot0 = c0)
#define OFF_BAR   76152832ull                 // u32 [4][64][32]: 1 flag per 128B line
#define N_FLAG_WORDS (4 * 64 * 32)

// Agent-scope relaxed (L1/L2-bypassing, meet-at-L3) accessors — r5/r8-proven.
__device__ __forceinline__ u64 cohload(const u64* p) {
  return __hip_atomic_load(p, __ATOMIC_RELAXED, __HIP_MEMORY_SCOPE_AGENT);
}
__device__ __forceinline__ void cohstore(u64* p, u64 v) {
  __hip_atomic_store(p, v, __ATOMIC_RELAXED, __HIP_MEMORY_SCOPE_AGENT);
}
__device__ __forceinline__ bf16x8 cohload_v8(const bf16* p) {
  union { u64 q[2]; bf16x8 v; } u;
  const u64* q = (const u64*)p;
  u.q[0] = cohload(q);
  u.q[1] = cohload(q + 1);
  return u.v;
}
__device__ __forceinline__ u32x4 cohload_q4(const bf16* p) {
  union { u64 q[2]; u32x4 v; } u;
  const u64* q = (const u64*)p;
  u.q[0] = cohload(q);
  u.q[1] = cohload(q + 1);
  return u.v;
}

// ---------------- prep: weights->bf16, EMB GATHER (r1-proven), h0/c0, flags=0 ----------------
__global__ void k_prep(const int* __restrict__ X, const float* __restrict__ emb,
                       const float* __restrict__ wih, const float* __restrict__ whh,
                       const float* __restrict__ wch, const float* __restrict__ wc2h,
                       const float* __restrict__ dw, const float* __restrict__ h0,
                       const float* __restrict__ c0, char* __restrict__ ws) {
  const long N_W = 4194304, N_DW = 65536, N_EMB = 16777216, N_S = 65536;
  const long TOT = N_W + N_DW + N_EMB + 2 * N_S + N_FLAG_WORDS;
  long stride = (long)gridDim.x * blockDim.x;
  for (long idx = (long)blockIdx.x * blockDim.x + threadIdx.x; idx < TOT; idx += stride) {
    if (idx < N_W) {
      long m = idx >> 20, e = idx & 1048575;
      const float* s = (m == 0) ? wih : (m == 1) ? whh : (m == 2) ? wch : wc2h;
      ((bf16*)(ws + OFF_WIH))[idx] = (bf16)s[e];
    } else if (idx < N_W + N_DW) {
      long j = idx - N_W; long r = j >> 10, e = j & 1023;
      ((bf16*)(ws + OFF_DW))[j] = (bf16)((r < NTAGS) ? dw[r * 1024 + e] : 0.f);
    } else if (idx < N_W + N_DW + N_EMB) {        // gathered bf16 emb -> HISTB region
      long j = idx - N_W - N_DW; long i = j >> 10, e = j & 1023;
      ((bf16*)(ws + OFF_HISTB))[j] = (bf16)emb[(long)X[i] * 1024 + e];
    } else if (idx < N_W + N_DW + N_EMB + N_S) {  // HB slot0 = h0
      long j = idx - N_W - N_DW - N_EMB;
      ((bf16*)(ws + OFF_HB))[j] = (bf16)h0[j];
    } else if (idx < N_W + N_DW + N_EMB + 2 * N_S) {  // CB slot0 = c0
      long j = idx - N_W - N_DW - N_EMB - N_S;
      ((bf16*)(ws + OFF_CB))[j] = (bf16)c0[j];
    } else {                                      // flags = 0 (replay safety)
      long j = idx - N_W - N_DW - N_EMB - 2 * N_S;
      ((u32*)(ws + OFF_BAR))[j] = 0u;
    }
  }
}

// ---------------- XW = EMB @ Wih^T + b_ih + b_hh  (r1-proven form, bf16 A) ----------------
__global__ __launch_bounds__(256) void k_xw(const float* __restrict__ b_ih,
                                            const float* __restrict__ b_hh,
                                            char* __restrict__ ws) {
  const bf16* embb = (const bf16*)(ws + OFF_HISTB);   // gathered bf16 emb (staged by k_prep)
  const bf16* wih = (const bf16*)(ws + OFF_WIH);
  bf16* xw = (bf16*)(ws + OFF_XW);
  int l = threadIdx.x & 63, wv = threadIdx.x >> 6;
  int i0 = blockIdx.x * 64 + wv * 16;
  int h0 = blockIdx.y * 64;
  const bf16* ap = embb + (long)(i0 + (l & 15)) * 1024 + ((l >> 4) * 8);
  const bf16* bp = wih + (long)(h0 + (l & 15)) * 1024 + ((l >> 4) * 8);
  f32x4 zero = {0.f, 0.f, 0.f, 0.f};
  f32x4 acc[4] = {zero, zero, zero, zero};
  for (int k = 0; k < 1024; k += 32) {
    bf16x8 a = *(const bf16x8*)(ap + k);
#pragma unroll
    for (int j = 0; j < 4; ++j) {
      bf16x8 b = *(const bf16x8*)(bp + j * 16 * 1024 + k);
      acc[j] = __builtin_amdgcn_mfma_f32_16x16x32_bf16(a, b, acc[j], 0, 0, 0);
    }
  }
#pragma unroll
  for (int j = 0; j < 4; ++j)
#pragma unroll
    for (int r = 0; r < 4; ++r) {
      int row = i0 + (l >> 4) * 4 + r;
      int col = h0 + j * 16 + (l & 15);
      xw[(long)row * 1024 + col] = (bf16)(acc[j][r] + b_ih[col] + b_hh[col]);
    }
}

// ---------------- recurrence: 4 indep batch-groups x 64 blocks (r10-proven, verbatim) ----------------
// group g = blockIdx&3 owns batch rows [16g,16g+16); block j = blockIdx>>2 owns h-slice
// [16j,16j+16). 4 waves K-split (256 each).
//  (1) weights pinned in VGPRs with IN-LOOP asm (defeats rematerialization),
//  (2) phase-B c fragments carried in registers into next phase A,
//  (3) histb store tucked between flag-store and poll (hides under the wait).
// NOTE: histb (HISTB region) held gathered EMB until k_xw consumed it; k_rnn now
// overwrites it progressively with hy — safe, k_xw completed before k_rnn starts.
__global__ __launch_bounds__(256, 1) void k_rnn(const float* __restrict__ b_ch,
                                                const float* __restrict__ b_c2h,
                                                const float* __restrict__ c0,
                                                char* __restrict__ ws) {
  const bf16* xw = (const bf16*)(ws + OFF_XW);
  bf16* histb = (bf16*)(ws + OFF_HISTB);
  bf16* HB = (bf16*)(ws + OFF_HB);
  bf16* CB = (bf16*)(ws + OFF_CB);
  int g = blockIdx.x & 3, j = blockIdx.x >> 2;
  u32* flags = (u32*)(ws + OFF_BAR) + g * 64 * 32;

  int l = threadIdx.x & 63, wv = threadIdx.x >> 6;
  int b0 = g * 16, h0b = j * 16;
  int e = threadIdx.x;
  int eoff = (b0 + (e >> 4)) * 1024 + h0b + (e & 15);
  int gh = h0b + (e & 15);

  __shared__ float red[4][2][256];
  __shared__ bf16 xfer[256];   // 16x16 outgoing tile staging

  int lane_r = l & 15;
  int koff = wv * 256 + ((l >> 4) * 8);
  long arow = (long)(b0 + lane_r) * 1024 + koff;

  // weight fragments -> registers (96 VGPRs of bf16), plus rolling c fragments.
  u32x4 whh_r[8], wch_r[8], wc2h_r[8], cfr[8];
  {
    const bf16* p1 = (const bf16*)(ws + OFF_WHH)  + (long)(h0b + lane_r) * 1024 + koff;
    const bf16* p2 = (const bf16*)(ws + OFF_WCH)  + (long)(h0b + lane_r) * 1024 + koff;
    const bf16* p3 = (const bf16*)(ws + OFF_WC2H) + (long)(h0b + lane_r) * 1024 + koff;
#pragma unroll
    for (int kk = 0; kk < 8; ++kk) {
      whh_r[kk]  = *(const u32x4*)(p1 + kk * 32);
      wch_r[kk]  = *(const u32x4*)(p2 + kk * 32);
      wc2h_r[kk] = *(const u32x4*)(p3 + kk * 32);
      cfr[kk] = cohload_q4(CB + arow + kk * 32);   // c(0) from slot0
    }
  }

  float bch_v = b_ch[gh], bc2h_v = b_c2h[gh];
  float c_reg = c0[eoff];
  f32x4 zero = {0.f, 0.f, 0.f, 0.f};

  for (int t = 0; t < TT; ++t) {
    // In-loop pins: the empty asm "modifies" the frags every iteration, so the
    // compiler must keep them resident (cannot re-load from memory).
    asm volatile("" : "+v"(whh_r[0]), "+v"(whh_r[1]), "+v"(whh_r[2]), "+v"(whh_r[3]),
                      "+v"(whh_r[4]), "+v"(whh_r[5]), "+v"(whh_r[6]), "+v"(whh_r[7]),
                      "+v"(wch_r[0]), "+v"(wch_r[1]), "+v"(wch_r[2]), "+v"(wch_r[3]),
                      "+v"(wch_r[4]), "+v"(wch_r[5]), "+v"(wch_r[6]), "+v"(wch_r[7]));
    asm volatile("" : "+v"(wc2h_r[0]), "+v"(wc2h_r[1]), "+v"(wc2h_r[2]), "+v"(wc2h_r[3]),
                      "+v"(wc2h_r[4]), "+v"(wc2h_r[5]), "+v"(wc2h_r[6]), "+v"(wc2h_r[7]));
    asm volatile("" : "+v"(cfr[0]), "+v"(cfr[1]), "+v"(cfr[2]), "+v"(cfr[3]),
                      "+v"(cfr[4]), "+v"(cfr[5]), "+v"(cfr[6]), "+v"(cfr[7]));

    long slot1 = (long)((t + 1) & 1) * 65536;
    float xwv = (float)xw[(long)t * 65536 + eoff];
    u32 tkA = 2u * t + 1u, tkB = 2u * t + 2u;
    const bf16* hx = HB + (long)(t & 1) * 65536;

    // ---- phase A: pre = h(t)@Whh (+xw), cg = c(t)@Wch (c frags already in regs)
    f32x4 ap_ = zero, ac_ = zero;
#pragma unroll
    for (int kk = 0; kk < 8; ++kk) {
      bf16x8 a1 = cohload_v8(hx + arow + kk * 32);
      ap_ = __builtin_amdgcn_mfma_f32_16x16x32_bf16(
          a1, __builtin_bit_cast(bf16x8, whh_r[kk]), ap_, 0, 0, 0);
      ac_ = __builtin_amdgcn_mfma_f32_16x16x32_bf16(
          __builtin_bit_cast(bf16x8, cfr[kk]), __builtin_bit_cast(bf16x8, wch_r[kk]), ac_, 0, 0, 0);
    }
#pragma unroll
    for (int r = 0; r < 4; ++r) {
      int ei = ((l >> 4) * 4 + r) * 16 + (l & 15);
      red[wv][0][ei] = ap_[r];
      red[wv][1][ei] = ac_[r];
    }
    __syncthreads();
    float pre = red[0][0][e] + red[1][0][e] + red[2][0][e] + red[3][0][e] + xwv;
    float cgm = red[0][1][e] + red[1][1][e] + red[2][1][e] + red[3][1][e] + bch_v;
    float gif = 1.f / (1.f + expf(-(pre + cgm)));
    float cy = gif * (c_reg + tanhf(pre));
    c_reg = cy;
    xfer[e] = (bf16)cy;
    __syncthreads();                    // xfer ready; red reads done
    if (e < 64)
      cohstore((u64*)(CB + slot1 + (long)(b0 + (e >> 2)) * 1024 + h0b) + (e & 3),
               ((u64*)xfer)[e]);
    asm volatile("s_waitcnt vmcnt(0)" ::: "memory");   // tile stores ack'd @L3
    if (e == 0)
      __hip_atomic_store(&flags[j * 32], tkA, __ATOMIC_RELAXED, __HIP_MEMORY_SCOPE_AGENT);
    if (e < 64) {
      const u32* my = &flags[e * 32];
      while (!__all(__hip_atomic_load(my, __ATOMIC_RELAXED, __HIP_MEMORY_SCOPE_AGENT) >= tkA))
        __builtin_amdgcn_s_sleep(1);
    }
    asm volatile("" ::: "memory");
    __syncthreads();

    // ---- phase B: o = cy(t+1)@Wc2h; keep cy frags for next step's phase A
    f32x4 ao = zero;
#pragma unroll
    for (int kk = 0; kk < 8; ++kk) {
      cfr[kk] = cohload_q4(CB + slot1 + arow + kk * 32);
      ao = __builtin_amdgcn_mfma_f32_16x16x32_bf16(
          __builtin_bit_cast(bf16x8, cfr[kk]), __builtin_bit_cast(bf16x8, wc2h_r[kk]), ao, 0, 0, 0);
    }
#pragma unroll
    for (int r = 0; r < 4; ++r)
      red[wv][0][((l >> 4) * 4 + r) * 16 + (l & 15)] = ao[r];
    __syncthreads();
    float o = red[0][0][e] + red[1][0][e] + red[2][0][e] + red[3][0][e] + bc2h_v;
    float og = 1.f / (1.f + expf(-(pre + o)));
    bf16 hb = (bf16)(og * tanhf(cy));
    xfer[e] = hb;
    __syncthreads();
    if (t < TT - 1) {
      if (e < 64)
        cohstore((u64*)(HB + slot1 + (long)(b0 + (e >> 2)) * 1024 + h0b) + (e & 3),
                 ((u64*)xfer)[e]);
      asm volatile("s_waitcnt vmcnt(0)" ::: "memory");
      if (e == 0)
        __hip_atomic_store(&flags[j * 32], tkB, __ATOMIC_RELAXED, __HIP_MEMORY_SCOPE_AGENT);
      histb[(long)t * 65536 + eoff] = hb;   // fire-and-forget; hides under the poll
      if (e < 64) {
        const u32* my = &flags[e * 32];
        while (!__all(__hip_atomic_load(my, __ATOMIC_RELAXED, __HIP_MEMORY_SCOPE_AGENT) >= tkB))
          __builtin_amdgcn_s_sleep(1);
      }
      asm volatile("" ::: "memory");
      __syncthreads();
    } else {
      histb[(long)t * 65536 + eoff] = hb;
    }
  }
}

// ---------------- dense + softmax ----------------
__global__ __launch_bounds__(256) void k_out(const float* __restrict__ dense_b,
                                             const char* __restrict__ ws,
                                             float* __restrict__ out) {
  const bf16* h  = (const bf16*)(ws + OFF_HISTB);  // slot t = hy at step t
  const bf16* dw = (const bf16*)(ws + OFF_DW);
  int l = threadIdx.x & 63, wv = threadIdx.x >> 6;
  int i0 = blockIdx.x * 64 + wv * 16;
  const bf16* ap = h  + (long)(i0 + (l & 15)) * 1024 + ((l >> 4) * 8);
  const bf16* bp = dw + (long)(l & 15) * 1024 + ((l >> 4) * 8);
  f32x4 zero = {0.f, 0.f, 0.f, 0.f};
  f32x4 acc[4] = {zero, zero, zero, zero};
  for (int k = 0; k < 1024; k += 32) {
    bf16x8 a = *(const bf16x8*)(ap + k);
#pragma unroll
    for (int j = 0; j < 4; ++j) {
      bf16x8 b = *(const bf16x8*)(bp + j * 16 * 1024 + k);
      acc[j] = __builtin_amdgcn_mfma_f32_16x16x32_bf16(a, b, acc[j], 0, 0, 0);
    }
  }
  int tag0 = l & 15;
#pragma unroll
  for (int r = 0; r < 4; ++r) {
    int row = i0 + (l >> 4) * 4 + r;
    float lg[4], ex[4];
    float mx = -1e30f;
#pragma unroll
    for (int j = 0; j < 4; ++j) {
      int tag = j * 16 + tag0;
      lg[j] = (tag < NTAGS) ? (acc[j][r] + dense_b[tag]) : -1e30f;
      mx = fmaxf(mx, lg[j]);
    }
    for (int m = 1; m < 16; m <<= 1) mx = fmaxf(mx, __shfl_xor(mx, m, 64));
    float s = 0.f;
#pragma unroll
    for (int j = 0; j < 4; ++j) {
      int tag = j * 16 + tag0;
      ex[j] = (tag < NTAGS) ? expf(lg[j] - mx) : 0.f;
      s += ex[j];
    }
    for (int m = 1; m < 16; m <<= 1) s += __shfl_xor(s, m, 64);
    float inv = 1.f / s;
#pragma unroll
    for (int j = 0; j < 4; ++j) {
      int tag = j * 16 + tag0;
      if (tag < NTAGS) out[(long)row * 50 + tag] = ex[j] * inv;
    }
  }
}

extern "C" void kernel_launch(void* const* d_in, const int* in_sizes, int n_in,
                              void* d_out, int out_size, void* d_ws, size_t ws_size,
                              hipStream_t stream) {
  const int*   X        = (const int*)d_in[0];
  // d_in[1] = lengths (unused; all == T)
  const float* embedding = (const float*)d_in[2];
  const float* w_ih  = (const float*)d_in[3];
  const float* w_hh  = (const float*)d_in[4];
  const float* w_ch  = (const float*)d_in[5];
  const float* w_c2h = (const float*)d_in[6];
  const float* b_ih  = (const float*)d_in[7];
  const float* b_hh  = (const float*)d_in[8];
  const float* b_ch  = (const float*)d_in[9];
  const float* b_c2h = (const float*)d_in[10];
  const float* dense_w = (const float*)d_in[11];
  const float* dense_b = (const float*)d_in[12];
  const float* h0 = (const float*)d_in[13];
  const float* c0 = (const float*)d_in[14];
  char* ws = (char*)d_ws;
  float* out = (float*)d_out;

  k_prep<<<4096, 256, 0, stream>>>(X, embedding, w_ih, w_hh, w_ch, w_c2h,
                                   dense_w, h0, c0, ws);
  k_xw<<<dim3(256, 16), 256, 0, stream>>>(b_ih, b_hh, ws);

  void* args[] = {(void*)&b_ch, (void*)&b_c2h, (void*)&c0, (void*)&ws};
  hipLaunchCooperativeKernel((const void*)k_rnn, dim3(256), dim3(256), args, 0, stream);

  k_out<<<256, 256, 0, stream>>>(dense_b, ws, out);
}

// Round 17
// 2253.333 us; speedup vs baseline: 1.3433x; 1.0068x over previous
//
#include <hip/hip_runtime.h>
#include <hip/hip_cooperative_groups.h>

typedef __bf16 bf16;
typedef __bf16 bf16x8 __attribute__((ext_vector_type(8)));
typedef float f32x4 __attribute__((ext_vector_type(4)));
typedef unsigned int u32;
typedef unsigned long long u64;
typedef unsigned int u32x4 __attribute__((ext_vector_type(4)));

// Problem dims
#define TT 256
#define NTAGS 50

// Workspace layout (bytes) — r8/r10-proven offsets
#define OFF_WIH   0ull                        // bf16 [1024][1024]
#define OFF_WHH   2097152ull
#define OFF_WCH   4194304ull
#define OFF_WC2H  6291456ull
#define OFF_DW    8388608ull                  // bf16 [64][1024] (tags padded to 64)
#define OFF_XW    8519680ull                  // bf16 [16384][1024]
#define OFF_HISTB 42074112ull                 // bf16 [256][64][1024]; ALSO reused as the
                                              // EMB staging buffer (k_prep gathers bf16 emb
                                              // here; k_xw consumes; k_rnn overwrites with hy)
#define OFF_HB    75628544ull                 // bf16 [2][64][1024] h cross-block (slot0 = h0)
#define OFF_CB    75890688ull                 // bf16 [2][64][1024] c cross-block (slot0 = c0)
#define OFF_BAR   76152832ull                 // u32 [4][64][32]: 1 flag per 128B line
#define N_FLAG_WORDS (4 * 64 * 32)

// Agent-scope relaxed (L1/L2-bypassing, meet-at-L3) accessors — r5/r8-proven.
__device__ __forceinline__ u64 cohload(const u64* p) {
  return __hip_atomic_load(p, __ATOMIC_RELAXED, __HIP_MEMORY_SCOPE_AGENT);
}
__device__ __forceinline__ void cohstore(u64* p, u64 v) {
  __hip_atomic_store(p, v, __ATOMIC_RELAXED, __HIP_MEMORY_SCOPE_AGENT);
}
__device__ __forceinline__ bf16x8 cohload_v8(const bf16* p) {
  union { u64 q[2]; bf16x8 v; } u;
  const u64* q = (const u64*)p;
  u.q[0] = cohload(q);
  u.q[1] = cohload(q + 1);
  return u.v;
}
__device__ __forceinline__ u32x4 cohload_q4(const bf16* p) {
  union { u64 q[2]; u32x4 v; } u;
  const u64* q = (const u64*)p;
  u.q[0] = cohload(q);
  u.q[1] = cohload(q + 1);
  return u.v;
}

// ---------------- prep: weights->bf16, EMB gather, h0/c0, flags=0 ----------------
__global__ void k_prep(const int* __restrict__ X, const float* __restrict__ emb,
                       const float* __restrict__ wih, const float* __restrict__ whh,
                       const float* __restrict__ wch, const float* __restrict__ wc2h,
                       const float* __restrict__ dw, const float* __restrict__ h0,
                       const float* __restrict__ c0, char* __restrict__ ws) {
  const long N_W = 4194304, N_DW = 65536, N_EMB = 16777216, N_S = 65536;
  const long TOT = N_W + N_DW + N_EMB + 2 * N_S + N_FLAG_WORDS;
  long stride = (long)gridDim.x * blockDim.x;
  for (long idx = (long)blockIdx.x * blockDim.x + threadIdx.x; idx < TOT; idx += stride) {
    if (idx < N_W) {
      long m = idx >> 20, e = idx & 1048575;
      const float* s = (m == 0) ? wih : (m == 1) ? whh : (m == 2) ? wch : wc2h;
      ((bf16*)(ws + OFF_WIH))[idx] = (bf16)s[e];
    } else if (idx < N_W + N_DW) {
      long j = idx - N_W; long r = j >> 10, e = j & 1023;
      ((bf16*)(ws + OFF_DW))[j] = (bf16)((r < NTAGS) ? dw[r * 1024 + e] : 0.f);
    } else if (idx < N_W + N_DW + N_EMB) {        // gathered bf16 emb -> HISTB region
      long j = idx - N_W - N_DW; long i = j >> 10, e = j & 1023;
      ((bf16*)(ws + OFF_HISTB))[j] = (bf16)emb[(long)X[i] * 1024 + e];
    } else if (idx < N_W + N_DW + N_EMB + N_S) {  // HB slot0 = h0
      long j = idx - N_W - N_DW - N_EMB;
      ((bf16*)(ws + OFF_HB))[j] = (bf16)h0[j];
    } else if (idx < N_W + N_DW + N_EMB + 2 * N_S) {  // CB slot0 = c0
      long j = idx - N_W - N_DW - N_EMB - N_S;
      ((bf16*)(ws + OFF_CB))[j] = (bf16)c0[j];
    } else {                                      // flags = 0 (replay safety)
      long j = idx - N_W - N_DW - N_EMB - 2 * N_S;
      ((u32*)(ws + OFF_BAR))[j] = 0u;
    }
  }
}

// ---------------- XW = EMB @ Wih^T + b_ih + b_hh  (r1-proven form, bf16 A) ----------------
__global__ __launch_bounds__(256) void k_xw(const float* __restrict__ b_ih,
                                            const float* __restrict__ b_hh,
                                            char* __restrict__ ws) {
  const bf16* embb = (const bf16*)(ws + OFF_HISTB);   // gathered bf16 emb (staged by k_prep)
  const bf16* wih = (const bf16*)(ws + OFF_WIH);
  bf16* xw = (bf16*)(ws + OFF_XW);
  int l = threadIdx.x & 63, wv = threadIdx.x >> 6;
  int i0 = blockIdx.x * 64 + wv * 16;
  int h0 = blockIdx.y * 64;
  const bf16* ap = embb + (long)(i0 + (l & 15)) * 1024 + ((l >> 4) * 8);
  const bf16* bp = wih + (long)(h0 + (l & 15)) * 1024 + ((l >> 4) * 8);
  f32x4 zero = {0.f, 0.f, 0.f, 0.f};
  f32x4 acc[4] = {zero, zero, zero, zero};
  for (int k = 0; k < 1024; k += 32) {
    bf16x8 a = *(const bf16x8*)(ap + k);
#pragma unroll
    for (int j = 0; j < 4; ++j) {
      bf16x8 b = *(const bf16x8*)(bp + j * 16 * 1024 + k);
      acc[j] = __builtin_amdgcn_mfma_f32_16x16x32_bf16(a, b, acc[j], 0, 0, 0);
    }
  }
#pragma unroll
  for (int j = 0; j < 4; ++j)
#pragma unroll
    for (int r = 0; r < 4; ++r) {
      int row = i0 + (l >> 4) * 4 + r;
      int col = h0 + j * 16 + (l & 15);
      xw[(long)row * 1024 + col] = (bf16)(acc[j][r] + b_ih[col] + b_hh[col]);
    }
}

// ---------------- recurrence: 4 indep batch-groups x 64 blocks ----------------
// r10-proven skeleton + SHUFFLE-PACK publish (new): instead of staging the outgoing
// 16x16 tile in LDS and having wave 0 relay it (write + barrier + 64 serial LDS reads),
// each lane shfl-gathers its 3 right-neighbors' bf16 (same row, cols c+1..c+3 = lanes
// l+1..l+3) and lanes with (l&3)==0 issue the u64 coherent store directly — stores now
// issue from all 4 waves in parallel immediately after the elementwise. Published bytes,
// protocol (store -> vmcnt(0) -> sync -> flag -> wide poll), and numerics bit-identical.
__global__ __launch_bounds__(256, 1) void k_rnn(const float* __restrict__ b_ch,
                                                const float* __restrict__ b_c2h,
                                                const float* __restrict__ c0,
                                                char* __restrict__ ws) {
  const bf16* xw = (const bf16*)(ws + OFF_XW);
  bf16* histb = (bf16*)(ws + OFF_HISTB);
  bf16* HB = (bf16*)(ws + OFF_HB);
  bf16* CB = (bf16*)(ws + OFF_CB);
  int g = blockIdx.x & 3, j = blockIdx.x >> 2;
  u32* flags = (u32*)(ws + OFF_BAR) + g * 64 * 32;

  int l = threadIdx.x & 63, wv = threadIdx.x >> 6;
  int b0 = g * 16, h0b = j * 16;
  int e = threadIdx.x;
  int eoff = (b0 + (e >> 4)) * 1024 + h0b + (e & 15);
  int gh = h0b + (e & 15);

  __shared__ float red[4][2][256];

  int lane_r = l & 15;
  int koff = wv * 256 + ((l >> 4) * 8);
  long arow = (long)(b0 + lane_r) * 1024 + koff;

  // shuffle-pack publish geometry: thread e owns element (row e>>4, col e&15);
  // lanes with (l&3)==0 store u64 covering cols (l&15)..(l&15)+3 of row wv*4+(l>>4).
  int prow = e >> 4, pcol = e & 15;
  u64* cb_dst = (u64*)(CB + (long)(b0 + prow) * 1024 + h0b + pcol);  // +slot1 at use
  u64* hb_dst = (u64*)(HB + (long)(b0 + prow) * 1024 + h0b + pcol);

  // weight fragments -> registers (96 VGPRs of bf16), plus rolling c fragments.
  u32x4 whh_r[8], wch_r[8], wc2h_r[8], cfr[8];
  {
    const bf16* p1 = (const bf16*)(ws + OFF_WHH)  + (long)(h0b + lane_r) * 1024 + koff;
    const bf16* p2 = (const bf16*)(ws + OFF_WCH)  + (long)(h0b + lane_r) * 1024 + koff;
    const bf16* p3 = (const bf16*)(ws + OFF_WC2H) + (long)(h0b + lane_r) * 1024 + koff;
#pragma unroll
    for (int kk = 0; kk < 8; ++kk) {
      whh_r[kk]  = *(const u32x4*)(p1 + kk * 32);
      wch_r[kk]  = *(const u32x4*)(p2 + kk * 32);
      wc2h_r[kk] = *(const u32x4*)(p3 + kk * 32);
      cfr[kk] = cohload_q4(CB + arow + kk * 32);   // c(0) from slot0
    }
  }

  float bch_v = b_ch[gh], bc2h_v = b_c2h[gh];
  float c_reg = c0[eoff];
  f32x4 zero = {0.f, 0.f, 0.f, 0.f};

  for (int t = 0; t < TT; ++t) {
    // In-loop pins: the empty asm "modifies" the frags every iteration, so the
    // compiler must keep them resident (cannot re-load from memory).
    asm volatile("" : "+v"(whh_r[0]), "+v"(whh_r[1]), "+v"(whh_r[2]), "+v"(whh_r[3]),
                      "+v"(whh_r[4]), "+v"(whh_r[5]), "+v"(whh_r[6]), "+v"(whh_r[7]),
                      "+v"(wch_r[0]), "+v"(wch_r[1]), "+v"(wch_r[2]), "+v"(wch_r[3]),
                      "+v"(wch_r[4]), "+v"(wch_r[5]), "+v"(wch_r[6]), "+v"(wch_r[7]));
    asm volatile("" : "+v"(wc2h_r[0]), "+v"(wc2h_r[1]), "+v"(wc2h_r[2]), "+v"(wc2h_r[3]),
                      "+v"(wc2h_r[4]), "+v"(wc2h_r[5]), "+v"(wc2h_r[6]), "+v"(wc2h_r[7]));
    asm volatile("" : "+v"(cfr[0]), "+v"(cfr[1]), "+v"(cfr[2]), "+v"(cfr[3]),
                      "+v"(cfr[4]), "+v"(cfr[5]), "+v"(cfr[6]), "+v"(cfr[7]));

    long slot1q = ((long)((t + 1) & 1) * 65536) >> 2;   // u64 index offset for slot1
    float xwv = (float)xw[(long)t * 65536 + eoff];
    u32 tkA = 2u * t + 1u, tkB = 2u * t + 2u;
    const bf16* hx = HB + (long)(t & 1) * 65536;

    // ---- phase A: pre = h(t)@Whh (+xw), cg = c(t)@Wch (c frags already in regs)
    f32x4 ap_ = zero, ac_ = zero;
#pragma unroll
    for (int kk = 0; kk < 8; ++kk) {
      bf16x8 a1 = cohload_v8(hx + arow + kk * 32);
      ap_ = __builtin_amdgcn_mfma_f32_16x16x32_bf16(
          a1, __builtin_bit_cast(bf16x8, whh_r[kk]), ap_, 0, 0, 0);
      ac_ = __builtin_amdgcn_mfma_f32_16x16x32_bf16(
          __builtin_bit_cast(bf16x8, cfr[kk]), __builtin_bit_cast(bf16x8, wch_r[kk]), ac_, 0, 0, 0);
    }
#pragma unroll
    for (int r = 0; r < 4; ++r) {
      int ei = ((l >> 4) * 4 + r) * 16 + (l & 15);
      red[wv][0][ei] = ap_[r];
      red[wv][1][ei] = ac_[r];
    }
    __syncthreads();
    float pre = red[0][0][e] + red[1][0][e] + red[2][0][e] + red[3][0][e] + xwv;
    float cgm = red[0][1][e] + red[1][1][e] + red[2][1][e] + red[3][1][e] + bch_v;
    float gif = 1.f / (1.f + expf(-(pre + cgm)));
    float cy = gif * (c_reg + tanhf(pre));
    c_reg = cy;
    // shuffle-pack publish: gather cols c+1..c+3 from lanes l+1..l+3, store u64
    {
      u32 v0 = (u32)__builtin_bit_cast(unsigned short, (bf16)cy);
      u32 v1 = (u32)__shfl((int)v0, l + 1, 64);
      u32 v2 = (u32)__shfl((int)v0, l + 2, 64);
      u32 v3 = (u32)__shfl((int)v0, l + 3, 64);
      if ((l & 3) == 0) {
        u64 pk = (u64)(v0 & 0xFFFFu) | ((u64)(v1 & 0xFFFFu) << 16)
               | ((u64)(v2 & 0xFFFFu) << 32) | ((u64)(v3 & 0xFFFFu) << 48);
        cohstore(cb_dst + slot1q, pk);
      }
    }
    asm volatile("s_waitcnt vmcnt(0)" ::: "memory");   // this wave's stores ack'd @L3
    __syncthreads();                                   // all waves ack'd
    if (e == 0)
      __hip_atomic_store(&flags[j * 32], tkA, __ATOMIC_RELAXED, __HIP_MEMORY_SCOPE_AGENT);
    if (e < 64) {
      const u32* my = &flags[e * 32];
      while (!__all(__hip_atomic_load(my, __ATOMIC_RELAXED, __HIP_MEMORY_SCOPE_AGENT) >= tkA))
        __builtin_amdgcn_s_sleep(1);
    }
    asm volatile("" ::: "memory");
    __syncthreads();

    // ---- phase B: o = cy(t+1)@Wc2h; keep cy frags for next step's phase A
    const bf16* cyp = CB + (long)((t + 1) & 1) * 65536;
    f32x4 ao = zero;
#pragma unroll
    for (int kk = 0; kk < 8; ++kk) {
      cfr[kk] = cohload_q4(cyp + arow + kk * 32);
      ao = __builtin_amdgcn_mfma_f32_16x16x32_bf16(
          __builtin_bit_cast(bf16x8, cfr[kk]), __builtin_bit_cast(bf16x8, wc2h_r[kk]), ao, 0, 0, 0);
    }
#pragma unroll
    for (int r = 0; r < 4; ++r)
      red[wv][0][((l >> 4) * 4 + r) * 16 + (l & 15)] = ao[r];
    __syncthreads();
    float o = red[0][0][e] + red[1][0][e] + red[2][0][e] + red[3][0][e] + bc2h_v;
    float og = 1.f / (1.f + expf(-(pre + o)));
    bf16 hb = (bf16)(og * tanhf(cy));
    if (t < TT - 1) {
      u32 v0 = (u32)__builtin_bit_cast(unsigned short, hb);
      u32 v1 = (u32)__shfl((int)v0, l + 1, 64);
      u32 v2 = (u32)__shfl((int)v0, l + 2, 64);
      u32 v3 = (u32)__shfl((int)v0, l + 3, 64);
      if ((l & 3) == 0) {
        u64 pk = (u64)(v0 & 0xFFFFu) | ((u64)(v1 & 0xFFFFu) << 16)
               | ((u64)(v2 & 0xFFFFu) << 32) | ((u64)(v3 & 0xFFFFu) << 48);
        cohstore(hb_dst + slot1q, pk);
      }
      asm volatile("s_waitcnt vmcnt(0)" ::: "memory");
      __syncthreads();
      if (e == 0)
        __hip_atomic_store(&flags[j * 32], tkB, __ATOMIC_RELAXED, __HIP_MEMORY_SCOPE_AGENT);
      histb[(long)t * 65536 + eoff] = hb;   // fire-and-forget; hides under the poll
      if (e < 64) {
        const u32* my = &flags[e * 32];
        while (!__all(__hip_atomic_load(my, __ATOMIC_RELAXED, __HIP_MEMORY_SCOPE_AGENT) >= tkB))
          __builtin_amdgcn_s_sleep(1);
      }
      asm volatile("" ::: "memory");
      __syncthreads();
    } else {
      histb[(long)t * 65536 + eoff] = hb;
    }
  }
}

// ---------------- dense + softmax ----------------
__global__ __launch_bounds__(256) void k_out(const float* __restrict__ dense_b,
                                             const char* __restrict__ ws,
                                             float* __restrict__ out) {
  const bf16* h  = (const bf16*)(ws + OFF_HISTB);  // slot t = hy at step t
  const bf16* dw = (const bf16*)(ws + OFF_DW);
  int l = threadIdx.x & 63, wv = threadIdx.x >> 6;
  int i0 = blockIdx.x * 64 + wv * 16;
  const bf16* ap = h  + (long)(i0 + (l & 15)) * 1024 + ((l >> 4) * 8);
  const bf16* bp = dw + (long)(l & 15) * 1024 + ((l >> 4) * 8);
  f32x4 zero = {0.f, 0.f, 0.f, 0.f};
  f32x4 acc[4] = {zero, zero, zero, zero};
  for (int k = 0; k < 1024; k += 32) {
    bf16x8 a = *(const bf16x8*)(ap + k);
#pragma unroll
    for (int j = 0; j < 4; ++j) {
      bf16x8 b = *(const bf16x8*)(bp + j * 16 * 1024 + k);
      acc[j] = __builtin_amdgcn_mfma_f32_16x16x32_bf16(a, b, acc[j], 0, 0, 0);
    }
  }
  int tag0 = l & 15;
#pragma unroll
  for (int r = 0; r < 4; ++r) {
    int row = i0 + (l >> 4) * 4 + r;
    float lg[4], ex[4];
    float mx = -1e30f;
#pragma unroll
    for (int j = 0; j < 4; ++j) {
      int tag = j * 16 + tag0;
      lg[j] = (tag < NTAGS) ? (acc[j][r] + dense_b[tag]) : -1e30f;
      mx = fmaxf(mx, lg[j]);
    }
    for (int m = 1; m < 16; m <<= 1) mx = fmaxf(mx, __shfl_xor(mx, m, 64));
    float s = 0.f;
#pragma unroll
    for (int j = 0; j < 4; ++j) {
      int tag = j * 16 + tag0;
      ex[j] = (tag < NTAGS) ? expf(lg[j] - mx) : 0.f;
      s += ex[j];
    }
    for (int m = 1; m < 16; m <<= 1) s += __shfl_xor(s, m, 64);
    float inv = 1.f / s;
#pragma unroll
    for (int j = 0; j < 4; ++j) {
      int tag = j * 16 + tag0;
      if (tag < NTAGS) out[(long)row * 50 + tag] = ex[j] * inv;
    }
  }
}

extern "C" void kernel_launch(void* const* d_in, const int* in_sizes, int n_in,
                              void* d_out, int out_size, void* d_ws, size_t ws_size,
                              hipStream_t stream) {
  const int*   X        = (const int*)d_in[0];
  // d_in[1] = lengths (unused; all == T)
  const float* embedding = (const float*)d_in[2];
  const float* w_ih  = (const float*)d_in[3];
  const float* w_hh  = (const float*)d_in[4];
  const float* w_ch  = (const float*)d_in[5];
  const float* w_c2h = (const float*)d_in[6];
  const float* b_ih  = (const float*)d_in[7];
  const float* b_hh  = (const float*)d_in[8];
  const float* b_ch  = (const float*)d_in[9];
  const float* b_c2h = (const float*)d_in[10];
  const float* dense_w = (const float*)d_in[11];
  const float* dense_b = (const float*)d_in[12];
  const float* h0 = (const float*)d_in[13];
  const float* c0 = (const float*)d_in[14];
  char* ws = (char*)d_ws;
  float* out = (float*)d_out;

  k_prep<<<4096, 256, 0, stream>>>(X, embedding, w_ih, w_hh, w_ch, w_c2h,
                                   dense_w, h0, c0, ws);
  k_xw<<<dim3(256, 16), 256, 0, stream>>>(b_ih, b_hh, ws);

  void* args[] = {(void*)&b_ch, (void*)&b_c2h, (void*)&c0, (void*)&ws};
  hipLaunchCooperativeKernel((const void*)k_rnn, dim3(256), dim3(256), args, 0, stream);

  k_out<<<256, 256, 0, stream>>>(dense_b, ws, out);
}